// Round 1
// 464.086 us; speedup vs baseline: 1.0368x; 1.0368x over previous
//
#include <hip/hip_runtime.h>

#define AS1 __attribute__((address_space(1)))
#define AS3 __attribute__((address_space(3)))

typedef unsigned short ushort_t;
typedef __attribute__((ext_vector_type(8))) short short8;
typedef __attribute__((ext_vector_type(4))) float floatx4;

__device__ __forceinline__ float bf2f(ushort_t h) {
    return __uint_as_float(((unsigned int)h) << 16);
}
__device__ __forceinline__ ushort_t f2bf(float f) {
    unsigned int u = __float_as_uint(f);
    u += 0x7fffu + ((u >> 16) & 1u);   // RNE
    return (ushort_t)(u >> 16);
}

// single merged fp32 -> bf16 cast over 5 arrays (float4 granularity)
__global__ __launch_bounds__(256) void cast_all(
    const float* __restrict__ s0, ushort_t* __restrict__ d0,   // x      2097152 f4
    const float* __restrict__ s1, ushort_t* __restrict__ d1,   // W_in   1048576
    const float* __restrict__ s2, ushort_t* __restrict__ d2,   // W_xp     49152
    const float* __restrict__ s3, ushort_t* __restrict__ d3,   // W_dt     32768
    const float* __restrict__ s4, ushort_t* __restrict__ d4)   // W_out   524288
{
    int i = blockIdx.x * 256 + threadIdx.x;
    const float* src; ushort_t* dst; int off;
    if      (i < 2097152) { src = s0; dst = d0; off = i; }
    else if (i < 3145728) { src = s1; dst = d1; off = i - 2097152; }
    else if (i < 3194880) { src = s2; dst = d2; off = i - 3145728; }
    else if (i < 3227648) { src = s3; dst = d3; off = i - 3194880; }
    else                  { src = s4; dst = d4; off = i - 3227648; }
    float4 v = ((const float4*)src)[off];
    ((ushort4*)dst)[off] = make_ushort4(f2bf(v.x), f2bf(v.y), f2bf(v.z), f2bf(v.w));
}

// ============================================================================
// 256x256x(BK=64) 8-wave "8-phase" GEMM (T2+T3+T4+T5 per learn_hip m201):
//   C[m,n] = sum_k A[m,k]*B[n,k];  requires M%256==0, N%256==0, K%64==0, K>=128.
//   512 thr = 8 waves (2M x 4N), per-wave out 128x64, acc[8][4] f32x4.
//   LDS 128KB: double-buffered 32KB A-tile + 32KB B-tile.
//   Swizzle: 16B granule hh = (tid&7)^(row&7) on the GLOBAL source column,
//   linear LDS dest (global_load_lds constraint), XOR on the ds_read address.
//   Schedule per K-tile t (buffers p=t&1, q=p^1):
//     ph0: ds_read a(rows wm..wm+63,s0/1)+b(n0..31)  | stage SLOT1(t+1,q) | bar | 16 MFMA | bar
//     ph1: ds_read b(n32..63)                        | stage SLOT2(t+1,q) | bar | 16 MFMA | bar
//     ph2: ds_read a(rows wm+64..127)                | stage SLOT3(t+1,q) | bar | 16 MFMA | bar
//     ph3: (regs only)                               | stage SLOT0(t+2,p) | 16 MFMA | vmcnt(2) | bar
//   vmcnt never drains to 0 in steady state (T4); setprio(1) brackets MFMA (T5).
// MODE 0: cols<2048 -> outH (xi bf16), cols>=2048 -> outH2 (z bf16)
// ============================================================================
template <int MODE>
__global__ __launch_bounds__(512, 2) void gemm8p(
    const ushort_t* __restrict__ A, int lda,
    const ushort_t* __restrict__ B, int ldb,
    int K, ushort_t* __restrict__ outH, ushort_t* __restrict__ outH2,
    int Mtiles, int Ntiles)
{
    __shared__ ushort_t sA[2][16384];   // [buf][256 rows * 64 cols]
    __shared__ ushort_t sB[2][16384];

    const int tid = threadIdx.x;

    // XCD-aware bijective swizzle (nwg % 8 == 0 guaranteed by caller)
    const int nwg = Mtiles * Ntiles;
    const int cpx = nwg >> 3;
    const int flat = blockIdx.x;
    const int swz = (flat & 7) * cpx + (flat >> 3);
    const int m0 = (swz % Mtiles) * 256;
    const int n0 = (swz / Mtiles) * 256;

    const int lane = tid & 63, wave = tid >> 6;
    const int wm = (wave >> 2) * 128, wn = (wave & 3) * 64;
    const int lm = lane & 15, quad = lane >> 4, lm7 = lane & 7;

    // staging bases: thread stages granule (r0, hh) of each 64-row chunk
    const int r0 = tid >> 3;
    const int hh = (tid & 7) ^ (r0 & 7);
    const ushort_t* pA = A + (size_t)(m0 + r0) * lda + hh * 8;
    const ushort_t* pB = B + (size_t)(n0 + r0) * ldb + hh * 8;

#define STG_A(buf, tt, rowoff)                                                        \
    __builtin_amdgcn_global_load_lds(                                                 \
        (const AS1 void*)(pA + (size_t)(rowoff) * lda + (tt) * 64),                   \
        (AS3 void*)(&sA[buf][(rowoff) * 64 + tid * 8]), 16, 0, 0)
#define STG_B(buf, tt, rowoff)                                                        \
    __builtin_amdgcn_global_load_lds(                                                 \
        (const AS1 void*)(pB + (size_t)(rowoff) * ldb + (tt) * 64),                   \
        (AS3 void*)(&sB[buf][(rowoff) * 64 + tid * 8]), 16, 0, 0)
#define SLOT0(buf, tt) { STG_A(buf, tt, 0);   STG_A(buf, tt, 64);  }
#define SLOT1(buf, tt) { STG_A(buf, tt, 128); STG_A(buf, tt, 192); }
#define SLOT2(buf, tt) { STG_B(buf, tt, 0);   STG_B(buf, tt, 64);  }
#define SLOT3(buf, tt) { STG_B(buf, tt, 128); STG_B(buf, tt, 192); }

#define LD_A(buf, h)                                                                  \
    { _Pragma("unroll")                                                               \
      for (int ii = 0; ii < 4; ++ii) {                                                \
          int row = wm + (h) * 64 + ii * 16 + lm;                                     \
          a_[ii][0] = *(const short8*)&sA[buf][(row * 8 + (quad ^ lm7)) * 8];         \
          a_[ii][1] = *(const short8*)&sA[buf][(row * 8 + ((4 + quad) ^ lm7)) * 8];   \
      } }
#define LD_B2(buf, j0)                                                                \
    { _Pragma("unroll")                                                               \
      for (int jj = 0; jj < 2; ++jj) {                                                \
          int row = wn + ((j0) + jj) * 16 + lm;                                       \
          b_[(j0) + jj][0] = *(const short8*)&sB[buf][(row * 8 + (quad ^ lm7)) * 8];  \
          b_[(j0) + jj][1] = *(const short8*)&sB[buf][(row * 8 + ((4 + quad) ^ lm7)) * 8]; \
      } }
#define MFMA16(i0, j0)                                                                \
    { __builtin_amdgcn_s_setprio(1);                                                  \
      _Pragma("unroll")                                                               \
      for (int ii = 0; ii < 4; ++ii) {                                                \
          _Pragma("unroll")                                                           \
          for (int jj = 0; jj < 2; ++jj) {                                            \
              acc[(i0) + ii][(j0) + jj] = __builtin_amdgcn_mfma_f32_16x16x32_bf16(    \
                  a_[ii][0], b_[(j0) + jj][0], acc[(i0) + ii][(j0) + jj], 0, 0, 0);   \
              acc[(i0) + ii][(j0) + jj] = __builtin_amdgcn_mfma_f32_16x16x32_bf16(    \
                  a_[ii][1], b_[(j0) + jj][1], acc[(i0) + ii][(j0) + jj], 0, 0, 0);   \
          } }                                                                         \
      __builtin_amdgcn_s_setprio(0); }

    floatx4 acc[8][4];
#pragma unroll
    for (int i = 0; i < 8; ++i)
#pragma unroll
        for (int j = 0; j < 4; ++j)
            acc[i][j] = (floatx4){0.f, 0.f, 0.f, 0.f};

    short8 a_[4][2], b_[4][2];
    const int NT = K >> 6;

    // prologue: full tile 0 into buf0, slot0 of tile 1 into buf1
    SLOT0(0, 0); SLOT1(0, 0); SLOT2(0, 0); SLOT3(0, 0);
    SLOT0(1, 1);
    asm volatile("s_waitcnt vmcnt(2)" ::: "memory");   // tile0's 8 loads done
    __builtin_amdgcn_s_barrier();

    for (int t = 0; t < NT; ++t) {
        const int p = t & 1, q = p ^ 1;
        // ---- phase 0: a half 0 + b cols 0..31
        LD_A(p, 0);
        LD_B2(p, 0);
        if (t + 1 < NT) SLOT1(q, t + 1);
        __builtin_amdgcn_s_barrier();
        MFMA16(0, 0);
        __builtin_amdgcn_s_barrier();
        // ---- phase 1: b cols 32..63
        LD_B2(p, 2);
        if (t + 1 < NT) SLOT2(q, t + 1);
        __builtin_amdgcn_s_barrier();
        MFMA16(0, 2);
        __builtin_amdgcn_s_barrier();
        // ---- phase 2: a half 1
        LD_A(p, 1);
        if (t + 1 < NT) SLOT3(q, t + 1);
        __builtin_amdgcn_s_barrier();
        MFMA16(4, 2);
        __builtin_amdgcn_s_barrier();
        // ---- phase 3: regs only; stage slot0 two tiles ahead into p (reads of p done)
        if (t + 2 < NT) SLOT0(p, t + 2);
        MFMA16(4, 0);
        if (t + 2 < NT) { asm volatile("s_waitcnt vmcnt(2)" ::: "memory"); }
        else            { asm volatile("s_waitcnt vmcnt(0)" ::: "memory"); }
        __builtin_amdgcn_s_barrier();
    }

    // epilogue (MODE 0): split bf16 store xi | z
#pragma unroll
    for (int idx = 0; idx < 8; ++idx) {
        const int rowb = m0 + wm + (idx >> 2) * 64 + (idx & 3) * 16 + quad * 4;
#pragma unroll
        for (int j = 0; j < 4; ++j) {
            const int col = n0 + wn + j * 16 + lm;
#pragma unroll
            for (int r = 0; r < 4; ++r) {
                float v = acc[idx][j][r];
                const size_t rr = (size_t)(rowb + r);
                if (MODE == 0) {
                    if (col < 2048) outH[rr * 2048 + col] = f2bf(v);
                    else            outH2[rr * 2048 + (col - 2048)] = f2bf(v);
                }
            }
        }
    }
#undef STG_A
#undef STG_B
#undef SLOT0
#undef SLOT1
#undef SLOT2
#undef SLOT3
#undef LD_A
#undef LD_B2
#undef MFMA16
}

// C[m,n] = sum_k A[m,k]*B[n,k];  A: M x lda bf16, B: N x ldb bf16.
// 128x128 tile, BK=64, XOR-swizzled LDS (granule hh = (g&7)^(row&7)) ->
// ds_read_b128 is 2-way-conflict max (free). 4 waves, wave = 64x64.
// MODE 2: softplus(acc + biasF[col]) -> fp16 (bits in outH)
// MODE 3: fp32 store col<Nact (final output)
// MODE 4: split-K partial (seg = blockIdx.y, n0 = 0): fp32 partial col<96
template <int MODE>
__global__ __launch_bounds__(256) void gemm_bt(
    const ushort_t* __restrict__ A, int lda,
    const ushort_t* __restrict__ B, int ldb,
    int K, int Nact, int ldc,
    float* __restrict__ outF, ushort_t* __restrict__ outH,
    ushort_t* __restrict__ outH2, const float* __restrict__ biasF)
{
    constexpr int BM = 128, BN = 128, BK = 64;
    __shared__ ushort_t sA[BM * BK];   // 16 KB, granule(16B)-swizzled
    __shared__ ushort_t sB[BN * BK];
    const int tid  = threadIdx.x;
    const int m0   = blockIdx.x * BM;
    const int seg  = (MODE == 4) ? blockIdx.y : 0;
    const int n0   = (MODE == 4) ? 0 : blockIdx.y * BN;
    if (MODE == 4) { A += seg * 512; B += seg * 512; }
    const int lane = tid & 63, wave = tid >> 6;
    const int wm   = (wave & 1) * 64, wn = (wave >> 1) * 64;
    const int lm   = lane & 15, quad = lane >> 4;
    const int lm7  = lane & 7;

    floatx4 acc[4][4];
#pragma unroll
    for (int i = 0; i < 4; ++i)
#pragma unroll
        for (int j = 0; j < 4; ++j)
            acc[i][j] = (floatx4){0.f, 0.f, 0.f, 0.f};

    for (int k0 = 0; k0 < K; k0 += BK) {
        __syncthreads();
#pragma unroll
        for (int r = 0; r < 4; ++r) {
            int g   = r * 256 + tid;            // granule index 0..1023
            int row = g >> 3;
            int hh  = (g & 7) ^ (row & 7);      // swizzled 16B-granule in row
            int col = k0 + hh * 8;
            const ushort_t* gA = A + (size_t)(m0 + row) * lda + col;
            __builtin_amdgcn_global_load_lds((const AS1 void*)gA, (AS3 void*)(&sA[g * 8]), 16, 0, 0);
            int rowB = n0 + row;
            if (rowB >= Nact) rowB = Nact - 1;  // clamp; garbage cols discarded in epilogue
            const ushort_t* gB = B + (size_t)rowB * ldb + col;
            __builtin_amdgcn_global_load_lds((const AS1 void*)gB, (AS3 void*)(&sB[g * 8]), 16, 0, 0);
        }
        __syncthreads();

#pragma unroll
        for (int s = 0; s < 2; ++s) {
            short8 af[4], bfr[4];
#pragma unroll
            for (int i = 0; i < 4; ++i) {
                int row = wm + i * 16 + lm;
                int gr  = row * 8 + ((s * 4 + quad) ^ lm7);
                af[i] = *(const short8*)&sA[gr * 8];
            }
#pragma unroll
            for (int j = 0; j < 4; ++j) {
                int row = wn + j * 16 + lm;
                int gr  = row * 8 + ((s * 4 + quad) ^ lm7);
                bfr[j] = *(const short8*)&sB[gr * 8];
            }
#pragma unroll
            for (int i = 0; i < 4; ++i)
#pragma unroll
                for (int j = 0; j < 4; ++j)
                    acc[i][j] = __builtin_amdgcn_mfma_f32_16x16x32_bf16(af[i], bfr[j], acc[i][j], 0, 0, 0);
        }
    }

#pragma unroll
    for (int i = 0; i < 4; ++i) {
#pragma unroll
        for (int j = 0; j < 4; ++j) {
#pragma unroll
            for (int r = 0; r < 4; ++r) {
                int row = m0 + wm + i * 16 + quad * 4 + r;
                int col = n0 + wn + j * 16 + lm;
                float v = acc[i][j][r];
                if (MODE == 2) {
                    float x  = v + biasF[col];
                    float sp = (x > 20.f) ? x : log1pf(__expf(x));
                    _Float16 hv = (_Float16)sp;
                    outH[(size_t)row * ldc + col] = *(ushort_t*)&hv;
                } else if (MODE == 3) {
                    if (col < Nact) outF[(size_t)row * ldc + col] = v;
                } else if (MODE == 4) {
                    if (col < 96)
                        outF[(size_t)seg * 786432 + (size_t)row * 96 + col] = v;
                }
            }
        }
    }
}

// combine split-K partials: dbl bf16 (8192x96) + B/C cols fp32 -> BCf (8192x32)
__global__ __launch_bounds__(256) void comb3(
    const float* __restrict__ Pg, ushort_t* __restrict__ dbl,
    float* __restrict__ BCf)
{
    int i = blockIdx.x * 256 + threadIdx.x;   // 0..786431
    float v = Pg[i] + Pg[i + 786432] + Pg[i + 2 * 786432] + Pg[i + 3 * 786432];
    dbl[i] = f2bf(v);
    int col = i % 96;
    if (col >= 64) BCf[(size_t)(i / 96) * 32 + (col - 64)] = v;
}

// u = silu(depthwise_causal_conv4(xi) + conv_b); 4 outputs along l per thread
__global__ __launch_bounds__(256) void conv_silu_k(
    const ushort_t* __restrict__ xi, const float* __restrict__ conv_w,
    const float* __restrict__ conv_b, ushort_t* __restrict__ u)
{
    int idx = blockIdx.x * 256 + threadIdx.x;  // 0..4194303
    int c   = idx & 2047;
    int lg  = idx >> 11;        // 0..2047
    int b   = lg >> 9;
    int l0  = (lg & 511) * 4;
    const size_t base = ((size_t)b * 2048 + l0) * 2048 + c;

    float w0 = conv_w[c * 4], w1 = conv_w[c * 4 + 1],
          w2 = conv_w[c * 4 + 2], w3 = conv_w[c * 4 + 3];
    float bias = conv_b[c];

    float xv[7];
#pragma unroll
    for (int j = 0; j < 3; ++j)
        xv[j] = (l0 - 3 + j >= 0) ? bf2f(xi[base + (j - 3) * 2048]) : 0.f;
#pragma unroll
    for (int j = 3; j < 7; ++j)
        xv[j] = bf2f(xi[base + (j - 3) * 2048]);

#pragma unroll
    for (int i = 0; i < 4; ++i) {
        float acc = bias + w0 * xv[i] + w1 * xv[i + 1] + w2 * xv[i + 2] + w3 * xv[i + 3];
        float s = acc / (1.f + __expf(-acc));
        u[base + i * 2048] = f2bf(s);
    }
}

// ---- chunked 2-pass parallel scan ------------------------------------------
// thread = (b, c, chunk); 16 states in registers; 32 chunks x 64 steps.
// grid: 1024 blocks = chunk(32) x b(4) x cblk(8); block = 256 threads over c.
// B/C read from global with WAVE-UNIFORM addresses -> compiler emits scalar
// s_load through the constant cache (free on VALU/LDS pipes). [R6: LDS staging
// of B/C regressed p2 83->123 us (spills + ds_read pipe); reverted.]
// carry layout: [chunk][s][b*2048+c] -> fully coalesced
constexpr int CH  = 64;
constexpr int NCH = 32;
constexpr int NI  = 4 * 2048 * 16;  // 131072

__global__ __launch_bounds__(256) void scan_p1(
    const _Float16* __restrict__ dt, const ushort_t* __restrict__ u,
    const float* __restrict__ BC, const float* __restrict__ A_log,
    float* __restrict__ Pbuf, float* __restrict__ Sbuf)
{
    const int tid   = threadIdx.x;
    const int blk   = blockIdx.x;
    const int chunk = blk >> 5;
    const int b     = (blk >> 3) & 3;
    const int c     = ((blk & 7) << 8) + tid;
    const size_t base = (size_t)b * 2048 + chunk * CH;

    float As[16];
#pragma unroll
    for (int s = 0; s < 16; ++s) As[s] = -__expf(A_log[c * 16 + s]);

    float S[16];
#pragma unroll
    for (int s = 0; s < 16; ++s) S[s] = 0.f;
    float cumdt = 0.f;

    for (int t = 0; t < CH; ++t) {
        const size_t r = base + t;
        float dtv = (float)dt[r * 2048 + c];
        float uv  = bf2f(u[r * 2048 + c]);
        float ct  = dtv * uv;
        cumdt += dtv;
#pragma unroll
        for (int s = 0; s < 16; ++s) {
            float a = __expf(dtv * As[s]);
            S[s] = fmaf(S[s], a, ct * BC[r * 32 + s]);
        }
    }
    const size_t ob = (size_t)chunk * NI + (size_t)b * 2048 + c;
#pragma unroll
    for (int s = 0; s < 16; ++s) {
        Pbuf[ob + (size_t)s * 8192] = __expf(As[s] * cumdt);  // prod of a over chunk
        Sbuf[ob + (size_t)s * 8192] = S[s];
    }
}

// serial fold of 32 chunk carries per (b,c,s); emits chunk-initial h
__global__ __launch_bounds__(256) void scan_comb(
    const float* __restrict__ Pbuf, const float* __restrict__ Sbuf,
    float* __restrict__ Hbuf)
{
    const int i = blockIdx.x * 256 + threadIdx.x;   // 0..NI-1 (= s*8192 + bc)
    float hi = 0.f;
#pragma unroll
    for (int k = 0; k < NCH; ++k) {
        Hbuf[(size_t)k * NI + i] = hi;
        hi = Sbuf[(size_t)k * NI + i] + Pbuf[(size_t)k * NI + i] * hi;
    }
}

// pass 2: replay chunk from h_init, y = (sum_s h*C + u*D) * silu(z), in-place over z
__global__ __launch_bounds__(256) void scan_p2(
    const _Float16* __restrict__ dt, const ushort_t* __restrict__ u,
    const float* __restrict__ BC, const float* __restrict__ A_log,
    const float* __restrict__ D_skip, const float* __restrict__ Hbuf,
    ushort_t* __restrict__ zy)
{
    const int tid   = threadIdx.x;
    const int blk   = blockIdx.x;
    const int chunk = blk >> 5;
    const int b     = (blk >> 3) & 3;
    const int c     = ((blk & 7) << 8) + tid;
    const size_t base = (size_t)b * 2048 + chunk * CH;

    float As[16], h[16];
#pragma unroll
    for (int s = 0; s < 16; ++s) As[s] = -__expf(A_log[c * 16 + s]);
    const float Dsk = D_skip[c];
    const size_t ob = (size_t)chunk * NI + (size_t)b * 2048 + c;
#pragma unroll
    for (int s = 0; s < 16; ++s) h[s] = Hbuf[ob + (size_t)s * 8192];

    for (int t = 0; t < CH; ++t) {
        const size_t r = base + t;
        float dtv = (float)dt[r * 2048 + c];
        float uv  = bf2f(u[r * 2048 + c]);
        float zv  = bf2f(zy[r * 2048 + c]);
        float ct  = dtv * uv;
        float p0 = 0.f, p1 = 0.f, p2 = 0.f, p3 = 0.f;
#pragma unroll
        for (int s = 0; s < 16; s += 4) {
            float a0 = __expf(dtv * As[s]);
            float a1 = __expf(dtv * As[s + 1]);
            float a2 = __expf(dtv * As[s + 2]);
            float a3 = __expf(dtv * As[s + 3]);
            h[s]     = fmaf(h[s],     a0, ct * BC[r * 32 + s]);
            h[s + 1] = fmaf(h[s + 1], a1, ct * BC[r * 32 + s + 1]);
            h[s + 2] = fmaf(h[s + 2], a2, ct * BC[r * 32 + s + 2]);
            h[s + 3] = fmaf(h[s + 3], a3, ct * BC[r * 32 + s + 3]);
            p0 = fmaf(h[s],     BC[r * 32 + 16 + s],     p0);
            p1 = fmaf(h[s + 1], BC[r * 32 + 16 + s + 1], p1);
            p2 = fmaf(h[s + 2], BC[r * 32 + 16 + s + 2], p2);
            p3 = fmaf(h[s + 3], BC[r * 32 + 16 + s + 3], p3);
        }
        float p = (p0 + p1) + (p2 + p3);
        float g = zv / (1.f + __expf(-zv));
        float yv = (p + uv * Dsk) * g;
        zy[r * 2048 + c] = f2bf(yv);
    }
}

extern "C" void kernel_launch(void* const* d_in, const int* in_sizes, int n_in,
                              void* d_out, int out_size, void* d_ws, size_t ws_size,
                              hipStream_t stream)
{
    const float* x      = (const float*)d_in[0];   // (4,2048,1024)
    const float* W_in   = (const float*)d_in[1];   // (4096,1024)
    const float* conv_w = (const float*)d_in[2];   // (2048,4)
    const float* conv_b = (const float*)d_in[3];   // (2048,)
    const float* W_xp   = (const float*)d_in[4];   // (96,2048)
    const float* W_dt   = (const float*)d_in[5];   // (2048,64)
    const float* b_dt   = (const float*)d_in[6];   // (2048,)
    const float* A_log  = (const float*)d_in[7];   // (2048,16)
    const float* D_skip = (const float*)d_in[8];   // (2048,)
    const float* W_out  = (const float*)d_in[9];   // (1024,2048)

    char* ws = (char*)d_ws;
    const size_t MB = 1024 * 1024;
    // phase 1: xi 0-32, xw 32-48, Wib 48-56
    // GEMM3 split-K partials Pg at 32-44.6 (xw dead by then)
    // after GEMM4: dt(fp16) 0-32; scan: Pb 32-48, Sb 48-64
    ushort_t*  xi  = (ushort_t*)(ws);
    ushort_t*  xw  = (ushort_t*)(ws + 32 * MB);
    ushort_t*  Wib = (ushort_t*)(ws + 48 * MB);
    _Float16*  dt  = (_Float16*)(ws);
    float*     Pg  = (float*)(ws + 32 * MB);       // 12.6MB split-K partials
    float*     Pb  = (float*)(ws + 32 * MB);
    float*     Sb  = (float*)(ws + 48 * MB);
    ushort_t*  z   = (ushort_t*)(ws + 64 * MB);    // 32MB
    ushort_t*  u   = (ushort_t*)(ws + 96 * MB);    // 32MB
    ushort_t*  dbl = (ushort_t*)(ws + 128 * MB);   // 1.5MB
    ushort_t*  Wxb = (ushort_t*)(ws + 130 * MB);
    ushort_t*  Wdb = (ushort_t*)(ws + 131 * MB);
    ushort_t*  Wob = (ushort_t*)(ws + 132 * MB);   // 4MB
    float*     BCf = (float*)(ws + 137 * MB);      // 1MB
    float*     Hb  = (float*)(ws + 138 * MB);      // 16MB -> ends 154MB

    // 0) all fp32 -> bf16 casts in one kernel
    cast_all<<<14656, 256, 0, stream>>>(x, xw, W_in, Wib, W_xp, Wxb, W_dt, Wdb, W_out, Wob);

    // 1) xz = x @ W_in^T : M=8192, N=4096, K=1024 -> xi bf16 | z bf16
    //    256^2 8-phase kernel: 512 blocks (32 Mtiles x 16 Ntiles), 512 thr
    gemm8p<0><<<512, 512, 0, stream>>>(xw, 1024, Wib, 1024, 1024, xi, z, 32, 16);
    // 2) u = silu(conv(xi)+b)
    conv_silu_k<<<16384, 256, 0, stream>>>(xi, conv_w, conv_b, u);
    // 3) dbl = u @ W_xproj^T, split-K x4 -> fp32 partials, then combine
    gemm_bt<4><<<dim3(64, 4), 256, 0, stream>>>(u, 2048, Wxb, 2048, 512, 96, 96,
                                                Pg, nullptr, nullptr, nullptr);
    comb3<<<3072, 256, 0, stream>>>(Pg, dbl, BCf);
    // 4) dt = softplus(dbl[:, :64] @ W_dt^T + b_dt) -> fp16 (overlays xi)
    gemm_bt<2><<<dim3(64, 16), 256, 0, stream>>>(dbl, 96, Wdb, 64, 64, 2048, 2048,
                                                 nullptr, (ushort_t*)dt, nullptr, b_dt);
    // 5) chunked parallel scan + gating; y overwrites z (bf16)
    scan_p1<<<1024, 256, 0, stream>>>(dt, u, BCf, A_log, Pb, Sb);
    scan_comb<<<512, 256, 0, stream>>>(Pb, Sb, Hb);
    scan_p2<<<1024, 256, 0, stream>>>(dt, u, BCf, A_log, D_skip, Hb, z);
    // 6) out = y @ W_out^T : M=8192, N=1024, K=2048 -> fp32 d_out
    gemm_bt<3><<<dim3(64, 8), 256, 0, stream>>>(z, 2048, Wob, 2048, 2048, 1024, 1024,
                                                (float*)d_out, nullptr, nullptr, nullptr);
}

// Round 2
// 461.670 us; speedup vs baseline: 1.0422x; 1.0052x over previous
//
#include <hip/hip_runtime.h>

#define AS1 __attribute__((address_space(1)))
#define AS3 __attribute__((address_space(3)))

typedef unsigned short ushort_t;
typedef __attribute__((ext_vector_type(8))) short short8;
typedef __attribute__((ext_vector_type(4))) float floatx4;

__device__ __forceinline__ float bf2f(ushort_t h) {
    return __uint_as_float(((unsigned int)h) << 16);
}
__device__ __forceinline__ ushort_t f2bf(float f) {
    unsigned int u = __float_as_uint(f);
    u += 0x7fffu + ((u >> 16) & 1u);   // RNE
    return (ushort_t)(u >> 16);
}

// single merged fp32 -> bf16 cast over 5 arrays (float4 granularity)
__global__ __launch_bounds__(256) void cast_all(
    const float* __restrict__ s0, ushort_t* __restrict__ d0,   // x      2097152 f4
    const float* __restrict__ s1, ushort_t* __restrict__ d1,   // W_in   1048576
    const float* __restrict__ s2, ushort_t* __restrict__ d2,   // W_xp     49152
    const float* __restrict__ s3, ushort_t* __restrict__ d3,   // W_dt     32768
    const float* __restrict__ s4, ushort_t* __restrict__ d4)   // W_out   524288
{
    int i = blockIdx.x * 256 + threadIdx.x;
    const float* src; ushort_t* dst; int off;
    if      (i < 2097152) { src = s0; dst = d0; off = i; }
    else if (i < 3145728) { src = s1; dst = d1; off = i - 2097152; }
    else if (i < 3194880) { src = s2; dst = d2; off = i - 3145728; }
    else if (i < 3227648) { src = s3; dst = d3; off = i - 3194880; }
    else                  { src = s4; dst = d4; off = i - 3227648; }
    float4 v = ((const float4*)src)[off];
    ((ushort4*)dst)[off] = make_ushort4(f2bf(v.x), f2bf(v.y), f2bf(v.z), f2bf(v.w));
}

// ============================================================================
// 256x256x(BK=64) 8-wave "8-phase" GEMM (T2+T3+T4+T5 per learn_hip m201):
//   C[m,n] = sum_k A[m,k]*B[n,k];  requires Mtiles%8==0... specifically the
//   grid must be 32 Mtiles x 16 Ntiles (512 blocks) for the region map below.
//   512 thr = 8 waves (2M x 4N), per-wave out 128x64, acc[8][4] f32x4.
//   LDS 128KB: double-buffered 32KB A-tile + 32KB B-tile.
//   Swizzle: 16B granule hh = (tid&7)^(row&7) on the GLOBAL source column,
//   linear LDS dest (global_load_lds constraint), XOR on the ds_read address.
//
//   Block->tile map [R2]: per-XCD compact 8x8 tile regions. Old map gave each
//   XCD a 32Mx2N strip = 17MB/XCD unique footprint -> FETCH 135MB (= 8x17,
//   model-exact) and stage-latency stalls (MfmaUtil 32%). New map: XCD x =
//   flat&7 owns region (rM=x>>1, rN=x&1) of 8x8 tiles = 8MB/XCD; k=flat>>3
//   walks m=k>>3 (so a round of 32 CUs covers 4Mx8N = 6MB, mostly L2-resident).
//
//   Schedule per K-tile t (buffers p=t&1, q=p^1):
//     ph0: ds_read a(half0)+b(n0..31)  | stage SLOT1(t+1,q) | bar | 16 MFMA | bar
//     ph1: ds_read b(n32..63)          | stage SLOT2(t+1,q) | bar | 16 MFMA | bar
//     ph2: ds_read a(half1)            | stage SLOT3(t+1,q) | bar | 16 MFMA | bar
//     ph3: (regs only)                 | stage SLOT0(t+2,p) | 16 MFMA | vmcnt(2) | bar
//   vmcnt never drains to 0 in steady state (T4); setprio(1) brackets MFMA (T5).
// MODE 0: cols<2048 -> outH (xi bf16), cols>=2048 -> outH2 (z bf16)
// ============================================================================
template <int MODE>
__global__ __launch_bounds__(512, 2) void gemm8p(
    const ushort_t* __restrict__ A, int lda,
    const ushort_t* __restrict__ B, int ldb,
    int K, ushort_t* __restrict__ outH, ushort_t* __restrict__ outH2,
    int Mtiles, int Ntiles)
{
    __shared__ ushort_t sA[2][16384];   // [buf][256 rows * 64 cols]
    __shared__ ushort_t sB[2][16384];

    const int tid = threadIdx.x;

    // per-XCD 8x8 region map (requires Mtiles=32, Ntiles=16)
    const int xcd = blockIdx.x & 7;          // hw round-robins flat%8 -> XCD
    const int k8  = blockIdx.x >> 3;         // 0..63 within region
    const int m0  = (((xcd >> 1) << 3) + (k8 >> 3)) * 256;
    const int n0  = (((xcd & 1) << 3) + (k8 & 7)) * 256;

    const int lane = tid & 63, wave = tid >> 6;
    const int wm = (wave >> 2) * 128, wn = (wave & 3) * 64;
    const int lm = lane & 15, quad = lane >> 4, lm7 = lane & 7;

    // staging bases: thread stages granule (r0, hh) of each 64-row chunk
    const int r0 = tid >> 3;
    const int hh = (tid & 7) ^ (r0 & 7);
    const ushort_t* pA = A + (size_t)(m0 + r0) * lda + hh * 8;
    const ushort_t* pB = B + (size_t)(n0 + r0) * ldb + hh * 8;

#define STG_A(buf, tt, rowoff)                                                        \
    __builtin_amdgcn_global_load_lds(                                                 \
        (const AS1 void*)(pA + (size_t)(rowoff) * lda + (tt) * 64),                   \
        (AS3 void*)(&sA[buf][(rowoff) * 64 + tid * 8]), 16, 0, 0)
#define STG_B(buf, tt, rowoff)                                                        \
    __builtin_amdgcn_global_load_lds(                                                 \
        (const AS1 void*)(pB + (size_t)(rowoff) * ldb + (tt) * 64),                   \
        (AS3 void*)(&sB[buf][(rowoff) * 64 + tid * 8]), 16, 0, 0)
#define SLOT0(buf, tt) { STG_A(buf, tt, 0);   STG_A(buf, tt, 64);  }
#define SLOT1(buf, tt) { STG_A(buf, tt, 128); STG_A(buf, tt, 192); }
#define SLOT2(buf, tt) { STG_B(buf, tt, 0);   STG_B(buf, tt, 64);  }
#define SLOT3(buf, tt) { STG_B(buf, tt, 128); STG_B(buf, tt, 192); }

#define LD_A(buf, h)                                                                  \
    { _Pragma("unroll")                                                               \
      for (int ii = 0; ii < 4; ++ii) {                                                \
          int row = wm + (h) * 64 + ii * 16 + lm;                                     \
          a_[ii][0] = *(const short8*)&sA[buf][(row * 8 + (quad ^ lm7)) * 8];         \
          a_[ii][1] = *(const short8*)&sA[buf][(row * 8 + ((4 + quad) ^ lm7)) * 8];   \
      } }
#define LD_B2(buf, j0)                                                                \
    { _Pragma("unroll")                                                               \
      for (int jj = 0; jj < 2; ++jj) {                                                \
          int row = wn + ((j0) + jj) * 16 + lm;                                       \
          b_[(j0) + jj][0] = *(const short8*)&sB[buf][(row * 8 + (quad ^ lm7)) * 8];  \
          b_[(j0) + jj][1] = *(const short8*)&sB[buf][(row * 8 + ((4 + quad) ^ lm7)) * 8]; \
      } }
#define MFMA16(i0, j0)                                                                \
    { __builtin_amdgcn_s_setprio(1);                                                  \
      _Pragma("unroll")                                                               \
      for (int ii = 0; ii < 4; ++ii) {                                                \
          _Pragma("unroll")                                                           \
          for (int jj = 0; jj < 2; ++jj) {                                            \
              acc[(i0) + ii][(j0) + jj] = __builtin_amdgcn_mfma_f32_16x16x32_bf16(    \
                  a_[ii][0], b_[(j0) + jj][0], acc[(i0) + ii][(j0) + jj], 0, 0, 0);   \
              acc[(i0) + ii][(j0) + jj] = __builtin_amdgcn_mfma_f32_16x16x32_bf16(    \
                  a_[ii][1], b_[(j0) + jj][1], acc[(i0) + ii][(j0) + jj], 0, 0, 0);   \
          } }                                                                         \
      __builtin_amdgcn_s_setprio(0); }

    floatx4 acc[8][4];
#pragma unroll
    for (int i = 0; i < 8; ++i)
#pragma unroll
        for (int j = 0; j < 4; ++j)
            acc[i][j] = (floatx4){0.f, 0.f, 0.f, 0.f};

    short8 a_[4][2], b_[4][2];
    const int NT = K >> 6;

    // prologue: full tile 0 into buf0, slot0 of tile 1 into buf1
    SLOT0(0, 0); SLOT1(0, 0); SLOT2(0, 0); SLOT3(0, 0);
    SLOT0(1, 1);
    asm volatile("s_waitcnt vmcnt(2)" ::: "memory");   // tile0's 8 loads done
    __builtin_amdgcn_s_barrier();

    for (int t = 0; t < NT; ++t) {
        const int p = t & 1, q = p ^ 1;
        // ---- phase 0: a half 0 + b cols 0..31
        LD_A(p, 0);
        LD_B2(p, 0);
        if (t + 1 < NT) SLOT1(q, t + 1);
        __builtin_amdgcn_s_barrier();
        MFMA16(0, 0);
        __builtin_amdgcn_s_barrier();
        // ---- phase 1: b cols 32..63
        LD_B2(p, 2);
        if (t + 1 < NT) SLOT2(q, t + 1);
        __builtin_amdgcn_s_barrier();
        MFMA16(0, 2);
        __builtin_amdgcn_s_barrier();
        // ---- phase 2: a half 1
        LD_A(p, 1);
        if (t + 1 < NT) SLOT3(q, t + 1);
        __builtin_amdgcn_s_barrier();
        MFMA16(4, 2);
        __builtin_amdgcn_s_barrier();
        // ---- phase 3: regs only; stage slot0 two tiles ahead into p (reads of p done)
        if (t + 2 < NT) SLOT0(p, t + 2);
        MFMA16(4, 0);
        if (t + 2 < NT) { asm volatile("s_waitcnt vmcnt(2)" ::: "memory"); }
        else            { asm volatile("s_waitcnt vmcnt(0)" ::: "memory"); }
        __builtin_amdgcn_s_barrier();
    }

    // epilogue (MODE 0): split bf16 store xi | z
#pragma unroll
    for (int idx = 0; idx < 8; ++idx) {
        const int rowb = m0 + wm + (idx >> 2) * 64 + (idx & 3) * 16 + quad * 4;
#pragma unroll
        for (int j = 0; j < 4; ++j) {
            const int col = n0 + wn + j * 16 + lm;
#pragma unroll
            for (int r = 0; r < 4; ++r) {
                float v = acc[idx][j][r];
                const size_t rr = (size_t)(rowb + r);
                if (MODE == 0) {
                    if (col < 2048) outH[rr * 2048 + col] = f2bf(v);
                    else            outH2[rr * 2048 + (col - 2048)] = f2bf(v);
                }
            }
        }
    }
#undef STG_A
#undef STG_B
#undef SLOT0
#undef SLOT1
#undef SLOT2
#undef SLOT3
#undef LD_A
#undef LD_B2
#undef MFMA16
}

// C[m,n] = sum_k A[m,k]*B[n,k];  A: M x lda bf16, B: N x ldb bf16.
// 128x128 tile, BK=64, XOR-swizzled LDS (granule hh = (g&7)^(row&7)) ->
// ds_read_b128 is 2-way-conflict max (free). 4 waves, wave = 64x64.
// MODE 2: softplus(acc + biasF[col]) -> fp16 (bits in outH)
// MODE 3: fp32 store col<Nact (final output)
// MODE 4: split-K partial (seg = blockIdx.y, n0 = 0): fp32 partial col<96
template <int MODE>
__global__ __launch_bounds__(256) void gemm_bt(
    const ushort_t* __restrict__ A, int lda,
    const ushort_t* __restrict__ B, int ldb,
    int K, int Nact, int ldc,
    float* __restrict__ outF, ushort_t* __restrict__ outH,
    ushort_t* __restrict__ outH2, const float* __restrict__ biasF)
{
    constexpr int BM = 128, BN = 128, BK = 64;
    __shared__ ushort_t sA[BM * BK];   // 16 KB, granule(16B)-swizzled
    __shared__ ushort_t sB[BN * BK];
    const int tid  = threadIdx.x;
    const int m0   = blockIdx.x * BM;
    const int seg  = (MODE == 4) ? blockIdx.y : 0;
    const int n0   = (MODE == 4) ? 0 : blockIdx.y * BN;
    if (MODE == 4) { A += seg * 512; B += seg * 512; }
    const int lane = tid & 63, wave = tid >> 6;
    const int wm   = (wave & 1) * 64, wn = (wave >> 1) * 64;
    const int lm   = lane & 15, quad = lane >> 4;
    const int lm7  = lane & 7;

    floatx4 acc[4][4];
#pragma unroll
    for (int i = 0; i < 4; ++i)
#pragma unroll
        for (int j = 0; j < 4; ++j)
            acc[i][j] = (floatx4){0.f, 0.f, 0.f, 0.f};

    for (int k0 = 0; k0 < K; k0 += BK) {
        __syncthreads();
#pragma unroll
        for (int r = 0; r < 4; ++r) {
            int g   = r * 256 + tid;            // granule index 0..1023
            int row = g >> 3;
            int hh  = (g & 7) ^ (row & 7);      // swizzled 16B-granule in row
            int col = k0 + hh * 8;
            const ushort_t* gA = A + (size_t)(m0 + row) * lda + col;
            __builtin_amdgcn_global_load_lds((const AS1 void*)gA, (AS3 void*)(&sA[g * 8]), 16, 0, 0);
            int rowB = n0 + row;
            if (rowB >= Nact) rowB = Nact - 1;  // clamp; garbage cols discarded in epilogue
            const ushort_t* gB = B + (size_t)rowB * ldb + col;
            __builtin_amdgcn_global_load_lds((const AS1 void*)gB, (AS3 void*)(&sB[g * 8]), 16, 0, 0);
        }
        __syncthreads();

#pragma unroll
        for (int s = 0; s < 2; ++s) {
            short8 af[4], bfr[4];
#pragma unroll
            for (int i = 0; i < 4; ++i) {
                int row = wm + i * 16 + lm;
                int gr  = row * 8 + ((s * 4 + quad) ^ lm7);
                af[i] = *(const short8*)&sA[gr * 8];
            }
#pragma unroll
            for (int j = 0; j < 4; ++j) {
                int row = wn + j * 16 + lm;
                int gr  = row * 8 + ((s * 4 + quad) ^ lm7);
                bfr[j] = *(const short8*)&sB[gr * 8];
            }
#pragma unroll
            for (int i = 0; i < 4; ++i)
#pragma unroll
                for (int j = 0; j < 4; ++j)
                    acc[i][j] = __builtin_amdgcn_mfma_f32_16x16x32_bf16(af[i], bfr[j], acc[i][j], 0, 0, 0);
        }
    }

#pragma unroll
    for (int i = 0; i < 4; ++i) {
#pragma unroll
        for (int j = 0; j < 4; ++j) {
#pragma unroll
            for (int r = 0; r < 4; ++r) {
                int row = m0 + wm + i * 16 + quad * 4 + r;
                int col = n0 + wn + j * 16 + lm;
                float v = acc[i][j][r];
                if (MODE == 2) {
                    float x  = v + biasF[col];
                    float sp = (x > 20.f) ? x : log1pf(__expf(x));
                    _Float16 hv = (_Float16)sp;
                    outH[(size_t)row * ldc + col] = *(ushort_t*)&hv;
                } else if (MODE == 3) {
                    if (col < Nact) outF[(size_t)row * ldc + col] = v;
                } else if (MODE == 4) {
                    if (col < 96)
                        outF[(size_t)seg * 786432 + (size_t)row * 96 + col] = v;
                }
            }
        }
    }
}

// combine split-K partials: dbl bf16 (8192x96) + B/C cols fp32 -> BCf (8192x32)
__global__ __launch_bounds__(256) void comb3(
    const float* __restrict__ Pg, ushort_t* __restrict__ dbl,
    float* __restrict__ BCf)
{
    int i = blockIdx.x * 256 + threadIdx.x;   // 0..786431
    float v = Pg[i] + Pg[i + 786432] + Pg[i + 2 * 786432] + Pg[i + 3 * 786432];
    dbl[i] = f2bf(v);
    int col = i % 96;
    if (col >= 64) BCf[(size_t)(i / 96) * 32 + (col - 64)] = v;
}

// u = silu(depthwise_causal_conv4(xi) + conv_b); 4 outputs along l per thread
__global__ __launch_bounds__(256) void conv_silu_k(
    const ushort_t* __restrict__ xi, const float* __restrict__ conv_w,
    const float* __restrict__ conv_b, ushort_t* __restrict__ u)
{
    int idx = blockIdx.x * 256 + threadIdx.x;  // 0..4194303
    int c   = idx & 2047;
    int lg  = idx >> 11;        // 0..2047
    int b   = lg >> 9;
    int l0  = (lg & 511) * 4;
    const size_t base = ((size_t)b * 2048 + l0) * 2048 + c;

    float w0 = conv_w[c * 4], w1 = conv_w[c * 4 + 1],
          w2 = conv_w[c * 4 + 2], w3 = conv_w[c * 4 + 3];
    float bias = conv_b[c];

    float xv[7];
#pragma unroll
    for (int j = 0; j < 3; ++j)
        xv[j] = (l0 - 3 + j >= 0) ? bf2f(xi[base + (j - 3) * 2048]) : 0.f;
#pragma unroll
    for (int j = 3; j < 7; ++j)
        xv[j] = bf2f(xi[base + (j - 3) * 2048]);

#pragma unroll
    for (int i = 0; i < 4; ++i) {
        float acc = bias + w0 * xv[i] + w1 * xv[i + 1] + w2 * xv[i + 2] + w3 * xv[i + 3];
        float s = acc / (1.f + __expf(-acc));
        u[base + i * 2048] = f2bf(s);
    }
}

// ---- chunked 2-pass parallel scan ------------------------------------------
// thread = (b, c, chunk); 16 states in registers; 32 chunks x 64 steps.
// grid: 1024 blocks = chunk(32) x b(4) x cblk(8); block = 256 threads over c.
// B/C read from global with WAVE-UNIFORM addresses -> compiler emits scalar
// s_load through the constant cache (free on VALU/LDS pipes). [R6: LDS staging
// of B/C regressed p2 83->123 us (spills + ds_read pipe); reverted.]
// carry layout: [chunk][s][b*2048+c] -> fully coalesced
constexpr int CH  = 64;
constexpr int NCH = 32;
constexpr int NI  = 4 * 2048 * 16;  // 131072

__global__ __launch_bounds__(256) void scan_p1(
    const _Float16* __restrict__ dt, const ushort_t* __restrict__ u,
    const float* __restrict__ BC, const float* __restrict__ A_log,
    float* __restrict__ Pbuf, float* __restrict__ Sbuf)
{
    const int tid   = threadIdx.x;
    const int blk   = blockIdx.x;
    const int chunk = blk >> 5;
    const int b     = (blk >> 3) & 3;
    const int c     = ((blk & 7) << 8) + tid;
    const size_t base = (size_t)b * 2048 + chunk * CH;

    float As[16];
#pragma unroll
    for (int s = 0; s < 16; ++s) As[s] = -__expf(A_log[c * 16 + s]);

    float S[16];
#pragma unroll
    for (int s = 0; s < 16; ++s) S[s] = 0.f;
    float cumdt = 0.f;

    for (int t = 0; t < CH; ++t) {
        const size_t r = base + t;
        float dtv = (float)dt[r * 2048 + c];
        float uv  = bf2f(u[r * 2048 + c]);
        float ct  = dtv * uv;
        cumdt += dtv;
#pragma unroll
        for (int s = 0; s < 16; ++s) {
            float a = __expf(dtv * As[s]);
            S[s] = fmaf(S[s], a, ct * BC[r * 32 + s]);
        }
    }
    const size_t ob = (size_t)chunk * NI + (size_t)b * 2048 + c;
#pragma unroll
    for (int s = 0; s < 16; ++s) {
        Pbuf[ob + (size_t)s * 8192] = __expf(As[s] * cumdt);  // prod of a over chunk
        Sbuf[ob + (size_t)s * 8192] = S[s];
    }
}

// serial fold of 32 chunk carries per (b,c,s); emits chunk-initial h
__global__ __launch_bounds__(256) void scan_comb(
    const float* __restrict__ Pbuf, const float* __restrict__ Sbuf,
    float* __restrict__ Hbuf)
{
    const int i = blockIdx.x * 256 + threadIdx.x;   // 0..NI-1 (= s*8192 + bc)
    float hi = 0.f;
#pragma unroll
    for (int k = 0; k < NCH; ++k) {
        Hbuf[(size_t)k * NI + i] = hi;
        hi = Sbuf[(size_t)k * NI + i] + Pbuf[(size_t)k * NI + i] * hi;
    }
}

// pass 2: replay chunk from h_init, y = (sum_s h*C + u*D) * silu(z), in-place over z
__global__ __launch_bounds__(256) void scan_p2(
    const _Float16* __restrict__ dt, const ushort_t* __restrict__ u,
    const float* __restrict__ BC, const float* __restrict__ A_log,
    const float* __restrict__ D_skip, const float* __restrict__ Hbuf,
    ushort_t* __restrict__ zy)
{
    const int tid   = threadIdx.x;
    const int blk   = blockIdx.x;
    const int chunk = blk >> 5;
    const int b     = (blk >> 3) & 3;
    const int c     = ((blk & 7) << 8) + tid;
    const size_t base = (size_t)b * 2048 + chunk * CH;

    float As[16], h[16];
#pragma unroll
    for (int s = 0; s < 16; ++s) As[s] = -__expf(A_log[c * 16 + s]);
    const float Dsk = D_skip[c];
    const size_t ob = (size_t)chunk * NI + (size_t)b * 2048 + c;
#pragma unroll
    for (int s = 0; s < 16; ++s) h[s] = Hbuf[ob + (size_t)s * 8192];

    for (int t = 0; t < CH; ++t) {
        const size_t r = base + t;
        float dtv = (float)dt[r * 2048 + c];
        float uv  = bf2f(u[r * 2048 + c]);
        float zv  = bf2f(zy[r * 2048 + c]);
        float ct  = dtv * uv;
        float p0 = 0.f, p1 = 0.f, p2 = 0.f, p3 = 0.f;
#pragma unroll
        for (int s = 0; s < 16; s += 4) {
            float a0 = __expf(dtv * As[s]);
            float a1 = __expf(dtv * As[s + 1]);
            float a2 = __expf(dtv * As[s + 2]);
            float a3 = __expf(dtv * As[s + 3]);
            h[s]     = fmaf(h[s],     a0, ct * BC[r * 32 + s]);
            h[s + 1] = fmaf(h[s + 1], a1, ct * BC[r * 32 + s + 1]);
            h[s + 2] = fmaf(h[s + 2], a2, ct * BC[r * 32 + s + 2]);
            h[s + 3] = fmaf(h[s + 3], a3, ct * BC[r * 32 + s + 3]);
            p0 = fmaf(h[s],     BC[r * 32 + 16 + s],     p0);
            p1 = fmaf(h[s + 1], BC[r * 32 + 16 + s + 1], p1);
            p2 = fmaf(h[s + 2], BC[r * 32 + 16 + s + 2], p2);
            p3 = fmaf(h[s + 3], BC[r * 32 + 16 + s + 3], p3);
        }
        float p = (p0 + p1) + (p2 + p3);
        float g = zv / (1.f + __expf(-zv));
        float yv = (p + uv * Dsk) * g;
        zy[r * 2048 + c] = f2bf(yv);
    }
}

extern "C" void kernel_launch(void* const* d_in, const int* in_sizes, int n_in,
                              void* d_out, int out_size, void* d_ws, size_t ws_size,
                              hipStream_t stream)
{
    const float* x      = (const float*)d_in[0];   // (4,2048,1024)
    const float* W_in   = (const float*)d_in[1];   // (4096,1024)
    const float* conv_w = (const float*)d_in[2];   // (2048,4)
    const float* conv_b = (const float*)d_in[3];   // (2048,)
    const float* W_xp   = (const float*)d_in[4];   // (96,2048)
    const float* W_dt   = (const float*)d_in[5];   // (2048,64)
    const float* b_dt   = (const float*)d_in[6];   // (2048,)
    const float* A_log  = (const float*)d_in[7];   // (2048,16)
    const float* D_skip = (const float*)d_in[8];   // (2048,)
    const float* W_out  = (const float*)d_in[9];   // (1024,2048)

    char* ws = (char*)d_ws;
    const size_t MB = 1024 * 1024;
    // phase 1: xi 0-32, xw 32-48, Wib 48-56
    // GEMM3 split-K partials Pg at 32-44.6 (xw dead by then)
    // after GEMM4: dt(fp16) 0-32; scan: Pb 32-48, Sb 48-64
    ushort_t*  xi  = (ushort_t*)(ws);
    ushort_t*  xw  = (ushort_t*)(ws + 32 * MB);
    ushort_t*  Wib = (ushort_t*)(ws + 48 * MB);
    _Float16*  dt  = (_Float16*)(ws);
    float*     Pg  = (float*)(ws + 32 * MB);       // 12.6MB split-K partials
    float*     Pb  = (float*)(ws + 32 * MB);
    float*     Sb  = (float*)(ws + 48 * MB);
    ushort_t*  z   = (ushort_t*)(ws + 64 * MB);    // 32MB
    ushort_t*  u   = (ushort_t*)(ws + 96 * MB);    // 32MB
    ushort_t*  dbl = (ushort_t*)(ws + 128 * MB);   // 1.5MB
    ushort_t*  Wxb = (ushort_t*)(ws + 130 * MB);
    ushort_t*  Wdb = (ushort_t*)(ws + 131 * MB);
    ushort_t*  Wob = (ushort_t*)(ws + 132 * MB);   // 4MB
    float*     BCf = (float*)(ws + 137 * MB);      // 1MB
    float*     Hb  = (float*)(ws + 138 * MB);      // 16MB -> ends 154MB

    // 0) all fp32 -> bf16 casts in one kernel
    cast_all<<<14656, 256, 0, stream>>>(x, xw, W_in, Wib, W_xp, Wxb, W_dt, Wdb, W_out, Wob);

    // 1) xz = x @ W_in^T : M=8192, N=4096, K=1024 -> xi bf16 | z bf16
    //    256^2 8-phase kernel: 512 blocks (32 Mtiles x 16 Ntiles), 512 thr
    gemm8p<0><<<512, 512, 0, stream>>>(xw, 1024, Wib, 1024, 1024, xi, z, 32, 16);
    // 2) u = silu(conv(xi)+b)
    conv_silu_k<<<16384, 256, 0, stream>>>(xi, conv_w, conv_b, u);
    // 3) dbl = u @ W_xproj^T, split-K x4 -> fp32 partials, then combine
    gemm_bt<4><<<dim3(64, 4), 256, 0, stream>>>(u, 2048, Wxb, 2048, 512, 96, 96,
                                                Pg, nullptr, nullptr, nullptr);
    comb3<<<3072, 256, 0, stream>>>(Pg, dbl, BCf);
    // 4) dt = softplus(dbl[:, :64] @ W_dt^T + b_dt) -> fp16 (overlays xi)
    gemm_bt<2><<<dim3(64, 16), 256, 0, stream>>>(dbl, 96, Wdb, 64, 64, 2048, 2048,
                                                 nullptr, (ushort_t*)dt, nullptr, b_dt);
    // 5) chunked parallel scan + gating; y overwrites z (bf16)
    scan_p1<<<1024, 256, 0, stream>>>(dt, u, BCf, A_log, Pb, Sb);
    scan_comb<<<512, 256, 0, stream>>>(Pb, Sb, Hb);
    scan_p2<<<1024, 256, 0, stream>>>(dt, u, BCf, A_log, D_skip, Hb, z);
    // 6) out = y @ W_out^T : M=8192, N=1024, K=2048 -> fp32 d_out
    gemm_bt<3><<<dim3(64, 8), 256, 0, stream>>>(z, 2048, Wob, 2048, 2048, 1024, 1024,
                                                (float*)d_out, nullptr, nullptr, nullptr);
}

// Round 3
// 460.308 us; speedup vs baseline: 1.0453x; 1.0030x over previous
//
#include <hip/hip_runtime.h>

#define AS1 __attribute__((address_space(1)))
#define AS3 __attribute__((address_space(3)))

typedef unsigned short ushort_t;
typedef __attribute__((ext_vector_type(8))) short short8;
typedef __attribute__((ext_vector_type(4))) float floatx4;

__device__ __forceinline__ float bf2f(ushort_t h) {
    return __uint_as_float(((unsigned int)h) << 16);
}
__device__ __forceinline__ ushort_t f2bf(float f) {
    unsigned int u = __float_as_uint(f);
    u += 0x7fffu + ((u >> 16) & 1u);   // RNE
    return (ushort_t)(u >> 16);
}

// single merged fp32 -> bf16 cast over 5 arrays (float4 granularity)
__global__ __launch_bounds__(256) void cast_all(
    const float* __restrict__ s0, ushort_t* __restrict__ d0,   // x      2097152 f4
    const float* __restrict__ s1, ushort_t* __restrict__ d1,   // W_in   1048576
    const float* __restrict__ s2, ushort_t* __restrict__ d2,   // W_xp     49152
    const float* __restrict__ s3, ushort_t* __restrict__ d3,   // W_dt     32768
    const float* __restrict__ s4, ushort_t* __restrict__ d4)   // W_out   524288
{
    int i = blockIdx.x * 256 + threadIdx.x;
    const float* src; ushort_t* dst; int off;
    if      (i < 2097152) { src = s0; dst = d0; off = i; }
    else if (i < 3145728) { src = s1; dst = d1; off = i - 2097152; }
    else if (i < 3194880) { src = s2; dst = d2; off = i - 3145728; }
    else if (i < 3227648) { src = s3; dst = d3; off = i - 3194880; }
    else                  { src = s4; dst = d4; off = i - 3227648; }
    float4 v = ((const float4*)src)[off];
    ((ushort4*)dst)[off] = make_ushort4(f2bf(v.x), f2bf(v.y), f2bf(v.z), f2bf(v.w));
}

// ============================================================================
// 256x256x(BK=64) 8-wave GEMM, 2-barrier/K-tile drift schedule [R3]:
//   C[m,n] = sum_k A[m,k]*B[n,k];  grid must be 32 Mtiles x 16 Ntiles.
//   512 thr = 8 waves (2M x 4N), per-wave out 128x64, acc[8][4] f32x4.
//   LDS 128KB: double-buffered 32KB A-tile + 32KB B-tile.
//   Swizzle: 16B granule hh = (tid&7)^(row&7) on the GLOBAL source column,
//   linear LDS dest (global_load_lds constraint), XOR on the ds_read address.
//   Block->tile map [R2]: per-XCD compact 8x8 tile regions (FETCH 135->49MB).
//
//   [R3] Only 2 barriers per K-tile (was 8; MfmaUtil 33% from lockstep):
//     hazard A (tile boundary): stages of t+1 landed before t+1 reads
//       -> vmcnt(2) + END barrier (SLOT0(t+2) stays in flight, never drain)
//     hazard B (rebuffer): all waves' ds_reads of buf p complete before
//       SLOT0(p,t+2) overwrites p -> MID barrier after last p-read cluster
//   Intra-tile phases removed: waves drift -> cross-wave MFMA/LDS overlap.
//   Stage issue rebalanced: SLOT1+2(t+1) at tile top (lead 4 ph), SLOT3 after
//   first MFMA cluster (lead 3 ph), SLOT0(t+2) after MID barrier (lead 6 ph).
//   Barriers are asm s_barrier + "memory" clobber (orders LDS/stage memory ops
//   without sched_barrier(0)-style full pinning).
// MODE 0: cols<2048 -> outH (xi bf16), cols>=2048 -> outH2 (z bf16)
// ============================================================================
template <int MODE>
__global__ __launch_bounds__(512, 2) void gemm8p(
    const ushort_t* __restrict__ A, int lda,
    const ushort_t* __restrict__ B, int ldb,
    int K, ushort_t* __restrict__ outH, ushort_t* __restrict__ outH2,
    int Mtiles, int Ntiles)
{
    __shared__ ushort_t sA[2][16384];   // [buf][256 rows * 64 cols]
    __shared__ ushort_t sB[2][16384];

    const int tid = threadIdx.x;

    // per-XCD 8x8 region map (requires Mtiles=32, Ntiles=16)
    const int xcd = blockIdx.x & 7;          // hw round-robins flat%8 -> XCD
    const int k8  = blockIdx.x >> 3;         // 0..63 within region
    const int m0  = (((xcd >> 1) << 3) + (k8 >> 3)) * 256;
    const int n0  = (((xcd & 1) << 3) + (k8 & 7)) * 256;

    const int lane = tid & 63, wave = tid >> 6;
    const int wm = (wave >> 2) * 128, wn = (wave & 3) * 64;
    const int lm = lane & 15, quad = lane >> 4, lm7 = lane & 7;

    // staging bases: thread stages granule (r0, hh) of each 64-row chunk
    const int r0 = tid >> 3;
    const int hh = (tid & 7) ^ (r0 & 7);
    const ushort_t* pA = A + (size_t)(m0 + r0) * lda + hh * 8;
    const ushort_t* pB = B + (size_t)(n0 + r0) * ldb + hh * 8;

#define STG_A(buf, tt, rowoff)                                                        \
    __builtin_amdgcn_global_load_lds(                                                 \
        (const AS1 void*)(pA + (size_t)(rowoff) * lda + (tt) * 64),                   \
        (AS3 void*)(&sA[buf][(rowoff) * 64 + tid * 8]), 16, 0, 0)
#define STG_B(buf, tt, rowoff)                                                        \
    __builtin_amdgcn_global_load_lds(                                                 \
        (const AS1 void*)(pB + (size_t)(rowoff) * ldb + (tt) * 64),                   \
        (AS3 void*)(&sB[buf][(rowoff) * 64 + tid * 8]), 16, 0, 0)
#define SLOT0(buf, tt) { STG_A(buf, tt, 0);   STG_A(buf, tt, 64);  }
#define SLOT1(buf, tt) { STG_A(buf, tt, 128); STG_A(buf, tt, 192); }
#define SLOT2(buf, tt) { STG_B(buf, tt, 0);   STG_B(buf, tt, 64);  }
#define SLOT3(buf, tt) { STG_B(buf, tt, 128); STG_B(buf, tt, 192); }

#define BARRIER() asm volatile("s_barrier" ::: "memory")

#define LD_A(buf, h)                                                                  \
    { _Pragma("unroll")                                                               \
      for (int ii = 0; ii < 4; ++ii) {                                                \
          int row = wm + (h) * 64 + ii * 16 + lm;                                     \
          a_[ii][0] = *(const short8*)&sA[buf][(row * 8 + (quad ^ lm7)) * 8];         \
          a_[ii][1] = *(const short8*)&sA[buf][(row * 8 + ((4 + quad) ^ lm7)) * 8];   \
      } }
#define LD_B2(buf, j0)                                                                \
    { _Pragma("unroll")                                                               \
      for (int jj = 0; jj < 2; ++jj) {                                                \
          int row = wn + ((j0) + jj) * 16 + lm;                                       \
          b_[(j0) + jj][0] = *(const short8*)&sB[buf][(row * 8 + (quad ^ lm7)) * 8];  \
          b_[(j0) + jj][1] = *(const short8*)&sB[buf][(row * 8 + ((4 + quad) ^ lm7)) * 8]; \
      } }
#define MFMA16(i0, j0)                                                                \
    { __builtin_amdgcn_s_setprio(1);                                                  \
      _Pragma("unroll")                                                               \
      for (int ii = 0; ii < 4; ++ii) {                                                \
          _Pragma("unroll")                                                           \
          for (int jj = 0; jj < 2; ++jj) {                                            \
              acc[(i0) + ii][(j0) + jj] = __builtin_amdgcn_mfma_f32_16x16x32_bf16(    \
                  a_[ii][0], b_[(j0) + jj][0], acc[(i0) + ii][(j0) + jj], 0, 0, 0);   \
              acc[(i0) + ii][(j0) + jj] = __builtin_amdgcn_mfma_f32_16x16x32_bf16(    \
                  a_[ii][1], b_[(j0) + jj][1], acc[(i0) + ii][(j0) + jj], 0, 0, 0);   \
          } }                                                                         \
      __builtin_amdgcn_s_setprio(0); }

    floatx4 acc[8][4];
#pragma unroll
    for (int i = 0; i < 8; ++i)
#pragma unroll
        for (int j = 0; j < 4; ++j)
            acc[i][j] = (floatx4){0.f, 0.f, 0.f, 0.f};

    short8 a_[4][2], b_[4][2];
    const int NT = K >> 6;

    // prologue: full tile 0 into buf0, slot0 of tile 1 into buf1
    SLOT0(0, 0); SLOT1(0, 0); SLOT2(0, 0); SLOT3(0, 0);
    SLOT0(1, 1);
    asm volatile("s_waitcnt vmcnt(2)" ::: "memory");   // tile0's 8 loads done
    BARRIER();

    for (int t = 0; t < NT; ++t) {
        const int p = t & 1, q = p ^ 1;
        // tile top: reads of p (staged), stages of t+1 into q (q fully read
        // during tile t-1; its last read completed before t-1's MID barrier)
        LD_A(p, 0);
        LD_B2(p, 0);
        if (t + 1 < NT) { SLOT1(q, t + 1); SLOT2(q, t + 1); }
        MFMA16(0, 0);
        LD_B2(p, 2);
        if (t + 1 < NT) { SLOT3(q, t + 1); }
        MFMA16(0, 2);
        LD_A(p, 1);
        MFMA16(4, 2);
        // MID barrier: every wave's ds_reads of p completed (lgkm drained
        // before MFMA16(4,2) consumed a_) -> safe to overwrite p
        BARRIER();
        if (t + 2 < NT) SLOT0(p, t + 2);
        MFMA16(4, 0);
        // END: tile t+1's stages (SLOT0 from t-1, SLOT1-3 from t) landed;
        // SLOT0(t+2) stays in flight (never drain in steady state)
        if (t + 2 < NT) { asm volatile("s_waitcnt vmcnt(2)" ::: "memory"); }
        else            { asm volatile("s_waitcnt vmcnt(0)" ::: "memory"); }
        BARRIER();
    }

    // epilogue (MODE 0): split bf16 store xi | z
#pragma unroll
    for (int idx = 0; idx < 8; ++idx) {
        const int rowb = m0 + wm + (idx >> 2) * 64 + (idx & 3) * 16 + quad * 4;
#pragma unroll
        for (int j = 0; j < 4; ++j) {
            const int col = n0 + wn + j * 16 + lm;
#pragma unroll
            for (int r = 0; r < 4; ++r) {
                float v = acc[idx][j][r];
                const size_t rr = (size_t)(rowb + r);
                if (MODE == 0) {
                    if (col < 2048) outH[rr * 2048 + col] = f2bf(v);
                    else            outH2[rr * 2048 + (col - 2048)] = f2bf(v);
                }
            }
        }
    }
#undef STG_A
#undef STG_B
#undef SLOT0
#undef SLOT1
#undef SLOT2
#undef SLOT3
#undef BARRIER
#undef LD_A
#undef LD_B2
#undef MFMA16
}

// C[m,n] = sum_k A[m,k]*B[n,k];  A: M x lda bf16, B: N x ldb bf16.
// 128x128 tile, BK=64, XOR-swizzled LDS (granule hh = (g&7)^(row&7)) ->
// ds_read_b128 is 2-way-conflict max (free). 4 waves, wave = 64x64.
// MODE 2: softplus(acc + biasF[col]) -> fp16 (bits in outH)
// MODE 3: fp32 store col<Nact (final output)
// MODE 4: split-K partial (seg = blockIdx.y, n0 = 0): fp32 partial col<96
template <int MODE>
__global__ __launch_bounds__(256) void gemm_bt(
    const ushort_t* __restrict__ A, int lda,
    const ushort_t* __restrict__ B, int ldb,
    int K, int Nact, int ldc,
    float* __restrict__ outF, ushort_t* __restrict__ outH,
    ushort_t* __restrict__ outH2, const float* __restrict__ biasF)
{
    constexpr int BM = 128, BN = 128, BK = 64;
    __shared__ ushort_t sA[BM * BK];   // 16 KB, granule(16B)-swizzled
    __shared__ ushort_t sB[BN * BK];
    const int tid  = threadIdx.x;
    const int m0   = blockIdx.x * BM;
    const int seg  = (MODE == 4) ? blockIdx.y : 0;
    const int n0   = (MODE == 4) ? 0 : blockIdx.y * BN;
    if (MODE == 4) { A += seg * 512; B += seg * 512; }
    const int lane = tid & 63, wave = tid >> 6;
    const int wm   = (wave & 1) * 64, wn = (wave >> 1) * 64;
    const int lm   = lane & 15, quad = lane >> 4;
    const int lm7  = lane & 7;

    floatx4 acc[4][4];
#pragma unroll
    for (int i = 0; i < 4; ++i)
#pragma unroll
        for (int j = 0; j < 4; ++j)
            acc[i][j] = (floatx4){0.f, 0.f, 0.f, 0.f};

    for (int k0 = 0; k0 < K; k0 += BK) {
        __syncthreads();
#pragma unroll
        for (int r = 0; r < 4; ++r) {
            int g   = r * 256 + tid;            // granule index 0..1023
            int row = g >> 3;
            int hh  = (g & 7) ^ (row & 7);      // swizzled 16B-granule in row
            int col = k0 + hh * 8;
            const ushort_t* gA = A + (size_t)(m0 + row) * lda + col;
            __builtin_amdgcn_global_load_lds((const AS1 void*)gA, (AS3 void*)(&sA[g * 8]), 16, 0, 0);
            int rowB = n0 + row;
            if (rowB >= Nact) rowB = Nact - 1;  // clamp; garbage cols discarded in epilogue
            const ushort_t* gB = B + (size_t)rowB * ldb + col;
            __builtin_amdgcn_global_load_lds((const AS1 void*)gB, (AS3 void*)(&sB[g * 8]), 16, 0, 0);
        }
        __syncthreads();

#pragma unroll
        for (int s = 0; s < 2; ++s) {
            short8 af[4], bfr[4];
#pragma unroll
            for (int i = 0; i < 4; ++i) {
                int row = wm + i * 16 + lm;
                int gr  = row * 8 + ((s * 4 + quad) ^ lm7);
                af[i] = *(const short8*)&sA[gr * 8];
            }
#pragma unroll
            for (int j = 0; j < 4; ++j) {
                int row = wn + j * 16 + lm;
                int gr  = row * 8 + ((s * 4 + quad) ^ lm7);
                bfr[j] = *(const short8*)&sB[gr * 8];
            }
#pragma unroll
            for (int i = 0; i < 4; ++i)
#pragma unroll
                for (int j = 0; j < 4; ++j)
                    acc[i][j] = __builtin_amdgcn_mfma_f32_16x16x32_bf16(af[i], bfr[j], acc[i][j], 0, 0, 0);
        }
    }

#pragma unroll
    for (int i = 0; i < 4; ++i) {
#pragma unroll
        for (int j = 0; j < 4; ++j) {
#pragma unroll
            for (int r = 0; r < 4; ++r) {
                int row = m0 + wm + i * 16 + quad * 4 + r;
                int col = n0 + wn + j * 16 + lm;
                float v = acc[i][j][r];
                if (MODE == 2) {
                    float x  = v + biasF[col];
                    float sp = (x > 20.f) ? x : log1pf(__expf(x));
                    _Float16 hv = (_Float16)sp;
                    outH[(size_t)row * ldc + col] = *(ushort_t*)&hv;
                } else if (MODE == 3) {
                    if (col < Nact) outF[(size_t)row * ldc + col] = v;
                } else if (MODE == 4) {
                    if (col < 96)
                        outF[(size_t)seg * 786432 + (size_t)row * 96 + col] = v;
                }
            }
        }
    }
}

// combine split-K partials: dbl bf16 (8192x96) + B/C cols fp32 -> BCf (8192x32)
__global__ __launch_bounds__(256) void comb3(
    const float* __restrict__ Pg, ushort_t* __restrict__ dbl,
    float* __restrict__ BCf)
{
    int i = blockIdx.x * 256 + threadIdx.x;   // 0..786431
    float v = Pg[i] + Pg[i + 786432] + Pg[i + 2 * 786432] + Pg[i + 3 * 786432];
    dbl[i] = f2bf(v);
    int col = i % 96;
    if (col >= 64) BCf[(size_t)(i / 96) * 32 + (col - 64)] = v;
}

// u = silu(depthwise_causal_conv4(xi) + conv_b); 4 outputs along l per thread
__global__ __launch_bounds__(256) void conv_silu_k(
    const ushort_t* __restrict__ xi, const float* __restrict__ conv_w,
    const float* __restrict__ conv_b, ushort_t* __restrict__ u)
{
    int idx = blockIdx.x * 256 + threadIdx.x;  // 0..4194303
    int c   = idx & 2047;
    int lg  = idx >> 11;        // 0..2047
    int b   = lg >> 9;
    int l0  = (lg & 511) * 4;
    const size_t base = ((size_t)b * 2048 + l0) * 2048 + c;

    float w0 = conv_w[c * 4], w1 = conv_w[c * 4 + 1],
          w2 = conv_w[c * 4 + 2], w3 = conv_w[c * 4 + 3];
    float bias = conv_b[c];

    float xv[7];
#pragma unroll
    for (int j = 0; j < 3; ++j)
        xv[j] = (l0 - 3 + j >= 0) ? bf2f(xi[base + (j - 3) * 2048]) : 0.f;
#pragma unroll
    for (int j = 3; j < 7; ++j)
        xv[j] = bf2f(xi[base + (j - 3) * 2048]);

#pragma unroll
    for (int i = 0; i < 4; ++i) {
        float acc = bias + w0 * xv[i] + w1 * xv[i + 1] + w2 * xv[i + 2] + w3 * xv[i + 3];
        float s = acc / (1.f + __expf(-acc));
        u[base + i * 2048] = f2bf(s);
    }
}

// ---- chunked 2-pass parallel scan ------------------------------------------
// thread = (b, c, chunk); 16 states in registers; 32 chunks x 64 steps.
// grid: 1024 blocks = chunk(32) x b(4) x cblk(8); block = 256 threads over c.
// B/C read from global with WAVE-UNIFORM addresses -> compiler emits scalar
// s_load through the constant cache (free on VALU/LDS pipes). [R6: LDS staging
// of B/C regressed p2 83->123 us (spills + ds_read pipe); reverted.]
// carry layout: [chunk][s][b*2048+c] -> fully coalesced
constexpr int CH  = 64;
constexpr int NCH = 32;
constexpr int NI  = 4 * 2048 * 16;  // 131072

__global__ __launch_bounds__(256) void scan_p1(
    const _Float16* __restrict__ dt, const ushort_t* __restrict__ u,
    const float* __restrict__ BC, const float* __restrict__ A_log,
    float* __restrict__ Pbuf, float* __restrict__ Sbuf)
{
    const int tid   = threadIdx.x;
    const int blk   = blockIdx.x;
    const int chunk = blk >> 5;
    const int b     = (blk >> 3) & 3;
    const int c     = ((blk & 7) << 8) + tid;
    const size_t base = (size_t)b * 2048 + chunk * CH;

    float As[16];
#pragma unroll
    for (int s = 0; s < 16; ++s) As[s] = -__expf(A_log[c * 16 + s]);

    float S[16];
#pragma unroll
    for (int s = 0; s < 16; ++s) S[s] = 0.f;
    float cumdt = 0.f;

    for (int t = 0; t < CH; ++t) {
        const size_t r = base + t;
        float dtv = (float)dt[r * 2048 + c];
        float uv  = bf2f(u[r * 2048 + c]);
        float ct  = dtv * uv;
        cumdt += dtv;
#pragma unroll
        for (int s = 0; s < 16; ++s) {
            float a = __expf(dtv * As[s]);
            S[s] = fmaf(S[s], a, ct * BC[r * 32 + s]);
        }
    }
    const size_t ob = (size_t)chunk * NI + (size_t)b * 2048 + c;
#pragma unroll
    for (int s = 0; s < 16; ++s) {
        Pbuf[ob + (size_t)s * 8192] = __expf(As[s] * cumdt);  // prod of a over chunk
        Sbuf[ob + (size_t)s * 8192] = S[s];
    }
}

// serial fold of 32 chunk carries per (b,c,s); emits chunk-initial h
__global__ __launch_bounds__(256) void scan_comb(
    const float* __restrict__ Pbuf, const float* __restrict__ Sbuf,
    float* __restrict__ Hbuf)
{
    const int i = blockIdx.x * 256 + threadIdx.x;   // 0..NI-1 (= s*8192 + bc)
    float hi = 0.f;
#pragma unroll
    for (int k = 0; k < NCH; ++k) {
        Hbuf[(size_t)k * NI + i] = hi;
        hi = Sbuf[(size_t)k * NI + i] + Pbuf[(size_t)k * NI + i] * hi;
    }
}

// pass 2: replay chunk from h_init, y = (sum_s h*C + u*D) * silu(z), in-place over z
__global__ __launch_bounds__(256) void scan_p2(
    const _Float16* __restrict__ dt, const ushort_t* __restrict__ u,
    const float* __restrict__ BC, const float* __restrict__ A_log,
    const float* __restrict__ D_skip, const float* __restrict__ Hbuf,
    ushort_t* __restrict__ zy)
{
    const int tid   = threadIdx.x;
    const int blk   = blockIdx.x;
    const int chunk = blk >> 5;
    const int b     = (blk >> 3) & 3;
    const int c     = ((blk & 7) << 8) + tid;
    const size_t base = (size_t)b * 2048 + chunk * CH;

    float As[16], h[16];
#pragma unroll
    for (int s = 0; s < 16; ++s) As[s] = -__expf(A_log[c * 16 + s]);
    const float Dsk = D_skip[c];
    const size_t ob = (size_t)chunk * NI + (size_t)b * 2048 + c;
#pragma unroll
    for (int s = 0; s < 16; ++s) h[s] = Hbuf[ob + (size_t)s * 8192];

    for (int t = 0; t < CH; ++t) {
        const size_t r = base + t;
        float dtv = (float)dt[r * 2048 + c];
        float uv  = bf2f(u[r * 2048 + c]);
        float zv  = bf2f(zy[r * 2048 + c]);
        float ct  = dtv * uv;
        float p0 = 0.f, p1 = 0.f, p2 = 0.f, p3 = 0.f;
#pragma unroll
        for (int s = 0; s < 16; s += 4) {
            float a0 = __expf(dtv * As[s]);
            float a1 = __expf(dtv * As[s + 1]);
            float a2 = __expf(dtv * As[s + 2]);
            float a3 = __expf(dtv * As[s + 3]);
            h[s]     = fmaf(h[s],     a0, ct * BC[r * 32 + s]);
            h[s + 1] = fmaf(h[s + 1], a1, ct * BC[r * 32 + s + 1]);
            h[s + 2] = fmaf(h[s + 2], a2, ct * BC[r * 32 + s + 2]);
            h[s + 3] = fmaf(h[s + 3], a3, ct * BC[r * 32 + s + 3]);
            p0 = fmaf(h[s],     BC[r * 32 + 16 + s],     p0);
            p1 = fmaf(h[s + 1], BC[r * 32 + 16 + s + 1], p1);
            p2 = fmaf(h[s + 2], BC[r * 32 + 16 + s + 2], p2);
            p3 = fmaf(h[s + 3], BC[r * 32 + 16 + s + 3], p3);
        }
        float p = (p0 + p1) + (p2 + p3);
        float g = zv / (1.f + __expf(-zv));
        float yv = (p + uv * Dsk) * g;
        zy[r * 2048 + c] = f2bf(yv);
    }
}

extern "C" void kernel_launch(void* const* d_in, const int* in_sizes, int n_in,
                              void* d_out, int out_size, void* d_ws, size_t ws_size,
                              hipStream_t stream)
{
    const float* x      = (const float*)d_in[0];   // (4,2048,1024)
    const float* W_in   = (const float*)d_in[1];   // (4096,1024)
    const float* conv_w = (const float*)d_in[2];   // (2048,4)
    const float* conv_b = (const float*)d_in[3];   // (2048,)
    const float* W_xp   = (const float*)d_in[4];   // (96,2048)
    const float* W_dt   = (const float*)d_in[5];   // (2048,64)
    const float* b_dt   = (const float*)d_in[6];   // (2048,)
    const float* A_log  = (const float*)d_in[7];   // (2048,16)
    const float* D_skip = (const float*)d_in[8];   // (2048,)
    const float* W_out  = (const float*)d_in[9];   // (1024,2048)

    char* ws = (char*)d_ws;
    const size_t MB = 1024 * 1024;
    // phase 1: xi 0-32, xw 32-48, Wib 48-56
    // GEMM3 split-K partials Pg at 32-44.6 (xw dead by then)
    // after GEMM4: dt(fp16) 0-32; scan: Pb 32-48, Sb 48-64
    ushort_t*  xi  = (ushort_t*)(ws);
    ushort_t*  xw  = (ushort_t*)(ws + 32 * MB);
    ushort_t*  Wib = (ushort_t*)(ws + 48 * MB);
    _Float16*  dt  = (_Float16*)(ws);
    float*     Pg  = (float*)(ws + 32 * MB);       // 12.6MB split-K partials
    float*     Pb  = (float*)(ws + 32 * MB);
    float*     Sb  = (float*)(ws + 48 * MB);
    ushort_t*  z   = (ushort_t*)(ws + 64 * MB);    // 32MB
    ushort_t*  u   = (ushort_t*)(ws + 96 * MB);    // 32MB
    ushort_t*  dbl = (ushort_t*)(ws + 128 * MB);   // 1.5MB
    ushort_t*  Wxb = (ushort_t*)(ws + 130 * MB);
    ushort_t*  Wdb = (ushort_t*)(ws + 131 * MB);
    ushort_t*  Wob = (ushort_t*)(ws + 132 * MB);   // 4MB
    float*     BCf = (float*)(ws + 137 * MB);      // 1MB
    float*     Hb  = (float*)(ws + 138 * MB);      // 16MB -> ends 154MB

    // 0) all fp32 -> bf16 casts in one kernel
    cast_all<<<14656, 256, 0, stream>>>(x, xw, W_in, Wib, W_xp, Wxb, W_dt, Wdb, W_out, Wob);

    // 1) xz = x @ W_in^T : M=8192, N=4096, K=1024 -> xi bf16 | z bf16
    //    256^2 2-barrier kernel: 512 blocks (32 Mtiles x 16 Ntiles), 512 thr
    gemm8p<0><<<512, 512, 0, stream>>>(xw, 1024, Wib, 1024, 1024, xi, z, 32, 16);
    // 2) u = silu(conv(xi)+b)
    conv_silu_k<<<16384, 256, 0, stream>>>(xi, conv_w, conv_b, u);
    // 3) dbl = u @ W_xproj^T, split-K x4 -> fp32 partials, then combine
    gemm_bt<4><<<dim3(64, 4), 256, 0, stream>>>(u, 2048, Wxb, 2048, 512, 96, 96,
                                                Pg, nullptr, nullptr, nullptr);
    comb3<<<3072, 256, 0, stream>>>(Pg, dbl, BCf);
    // 4) dt = softplus(dbl[:, :64] @ W_dt^T + b_dt) -> fp16 (overlays xi)
    gemm_bt<2><<<dim3(64, 16), 256, 0, stream>>>(dbl, 96, Wdb, 64, 64, 2048, 2048,
                                                 nullptr, (ushort_t*)dt, nullptr, b_dt);
    // 5) chunked parallel scan + gating; y overwrites z (bf16)
    scan_p1<<<1024, 256, 0, stream>>>(dt, u, BCf, A_log, Pb, Sb);
    scan_comb<<<512, 256, 0, stream>>>(Pb, Sb, Hb);
    scan_p2<<<1024, 256, 0, stream>>>(dt, u, BCf, A_log, D_skip, Hb, z);
    // 6) out = y @ W_out^T : M=8192, N=1024, K=2048 -> fp32 d_out
    gemm_bt<3><<<dim3(64, 8), 256, 0, stream>>>(z, 2048, Wob, 2048, 2048, 1024, 1024,
                                                (float*)d_out, nullptr, nullptr, nullptr);
}